// Round 27
// baseline (147.845 us; speedup 1.0000x reference)
//
#include <hip/hip_runtime.h>
#include <math.h>

#define NN 50000
#define EE 800000
#define DDIM 128
#define NROWS 100000   // B*N
#define NBIN 391       // ceil(NN/128) sort bins (128 dsts each)
#define NCHUNK 391     // ceil(EE/2048) edge chunks (2048 edges each)
#define GEMMB 1563     // ceil(NROWS/64)
#define CAP 4608       // scatterB LDS staging capacity (span ~2050 expected)

typedef __attribute__((ext_vector_type(8))) short bf16x8;
typedef __attribute__((ext_vector_type(4))) float f32x4;

__device__ __forceinline__ float lrelu(float x) { return x > 0.f ? x : 0.2f * x; }
// fast ELU via hardware v_exp_f32 (abs err ~1e-7, validated r13)
__device__ __forceinline__ float eluf(float x)  {
    float e = __expf(x);
    return x > 0.f ? x : e - 1.f;
}

__device__ __forceinline__ unsigned short f2bf(float f) {
    unsigned int u = __float_as_uint(f);
    u += 0x7fffu + ((u >> 16) & 1u);          // RNE
    return (unsigned short)(u >> 16);
}
__device__ __forceinline__ float bflo(unsigned int v) { return __uint_as_float(v << 16); }
__device__ __forceinline__ float bfhi(unsigned int v) { return __uint_as_float(v & 0xffff0000u); }

// ---------------------------------------------------------------------------
// histW: blocks [0,NCHUNK): per-chunk LDS histogram of dst>>7 -> private row
// histmat[chunk][bin]. Block NCHUNK: W fp32 -> bf16 pre-swizzled.
// ---------------------------------------------------------------------------
__global__ __launch_bounds__(256) void histW_kernel(const int* __restrict__ ei,
                                                    int* __restrict__ histmat,
                                                    const float* __restrict__ Wfc,
                                                    unsigned short* __restrict__ Wsw) {
    const int tid = threadIdx.x;
    if (blockIdx.x < NCHUNK) {
        __shared__ int lcnt[NBIN];
        for (int i = tid; i < NBIN; i += 256) lcnt[i] = 0;
        __syncthreads();
        const int cb  = blockIdx.x * 2048;
        const int cnt = min(2048, EE - cb);
#pragma unroll
        for (int r = 0; r < 8; ++r) {
            int el = r * 256 + tid;
            if (el < cnt) atomicAdd(&lcnt[ei[EE + cb + el] >> 7], 1);
        }
        __syncthreads();
        for (int i = tid; i < NBIN; i += 256)
            histmat[blockIdx.x * NBIN + i] = lcnt[i];
        return;
    }
    // W prep (one block)
    const int col = tid & 127;
    const int kh  = tid >> 7;                  // 0..1
#pragma unroll
    for (int q8 = 0; q8 < 8; ++q8) {
        int k0 = kh * 64 + q8 * 8;
        float4 w0 = *(const float4*)&Wfc[col * DDIM + k0];
        float4 w1 = *(const float4*)&Wfc[col * DDIM + k0 + 4];
        union { uint4 q4; unsigned short u[8]; } pk;
        pk.u[0] = f2bf(w0.x); pk.u[1] = f2bf(w0.y);
        pk.u[2] = f2bf(w0.z); pk.u[3] = f2bf(w0.w);
        pk.u[4] = f2bf(w1.x); pk.u[5] = f2bf(w1.y);
        pk.u[6] = f2bf(w1.z); pk.u[7] = f2bf(w1.w);
        int chunk = (k0 >> 3) ^ (col & 15);
        *(uint4*)((char*)Wsw + col * 256 + chunk * 16) = pk.q4;
    }
}

// ---------------------------------------------------------------------------
// colscan: one wave per bin — exclusive prefix over chunk counts.
// ---------------------------------------------------------------------------
__global__ __launch_bounds__(64) void colscan_kernel(const int* __restrict__ histmat,
                                                     int* __restrict__ chunkstart,
                                                     int* __restrict__ bintot) {
    const int bin  = blockIdx.x;
    const int lane = threadIdx.x;
    int carry = 0;
#pragma unroll
    for (int it = 0; it < 7; ++it) {           // 7*64 = 448 >= NCHUNK
        int c = it * 64 + lane;
        int v = (c < NCHUNK) ? histmat[c * NBIN + bin] : 0;
        int x = v;
#pragma unroll
        for (int o = 1; o < 64; o <<= 1) {
            int t = __shfl_up(x, o);
            if (lane >= o) x += t;
        }
        if (c < NCHUNK) chunkstart[bin * NCHUNK + c] = carry + x - v;
        carry += __shfl(x, 63);
    }
    if (lane == 0) bintot[bin] = carry;
}

// ---------------------------------------------------------------------------
// fusedAG: blocks [0,NCHUNK) = scatterA; blocks [NCHUNK,+GEMMB) = MFMA gemm.
// ---------------------------------------------------------------------------
__global__ __launch_bounds__(256) void fusedAG_kernel(const int* __restrict__ ei,
                                                      const int* __restrict__ bintot,
                                                      const int* __restrict__ chunkstart,
                                                      unsigned int* __restrict__ records,
                                                      const float* __restrict__ h,
                                                      const unsigned short* __restrict__ Wsw,
                                                      const float* __restrict__ Wat,
                                                      unsigned short* __restrict__ Wh16,
                                                      float* __restrict__ ssrc,
                                                      float* __restrict__ sdst) {
    __shared__ unsigned int Wlds_u32[8192];    // 32 KB: gemm W / scatterA tables
    __shared__ unsigned short stage[64 * 136]; // 17408 B (gemm epilogue)
    const int tid = threadIdx.x;

    if (blockIdx.x < NCHUNK) {
        // ---- scatterA path ----
        int* lcnt  = (int*)Wlds_u32;           // [0, 391)
        int* lbase = (int*)Wlds_u32 + 512;     // [512, 903)
        int* bb    = (int*)Wlds_u32 + 1024;    // [1024, 1415)
        if (tid < 64) {                        // wave0: excl scan of bintot
            int carry = 0;
#pragma unroll
            for (int it = 0; it < 7; ++it) {
                int c = it * 64 + tid;
                int v = (c < NBIN) ? bintot[c] : 0;
                int x = v;
#pragma unroll
                for (int o = 1; o < 64; o <<= 1) {
                    int t = __shfl_up(x, o);
                    if (tid >= o) x += t;
                }
                if (c < NBIN) bb[c] = carry + x - v;
                carry += __shfl(x, 63);
            }
        }
        __syncthreads();
        for (int i = tid; i < NBIN; i += 256) {
            lcnt[i]  = 0;
            lbase[i] = bb[i] + chunkstart[i * NCHUNK + blockIdx.x];
        }
        __syncthreads();
        const int cb  = blockIdx.x * 2048;
        const int cnt = min(2048, EE - cb);
#pragma unroll
        for (int r = 0; r < 8; ++r) {
            int el = r * 256 + tid;
            if (el < cnt) {
                int e   = cb + el;
                int dst = ei[EE + e];
                int src = ei[e];
                int bin = dst >> 7;
                int rank = atomicAdd(&lcnt[bin], 1);
                records[lbase[bin] + rank] = (unsigned)src | ((unsigned)(dst & 127) << 16);
            }
        }
        return;
    }

    // ---- gemm path (r25 proven) ----
    char* WldsB  = (char*)Wlds_u32;
    char* stageB = (char*)stage;
    const int gb   = blockIdx.x - NCHUNK;
    const int lane = tid & 63;
    const int wv   = tid >> 6;

    {
        const char* gsrc = (const char*)Wsw + wv * 8192 + lane * 16;
        unsigned int* ldst = &Wlds_u32[wv * 2048];
#pragma unroll
        for (int c8 = 0; c8 < 8; ++c8) {
            __builtin_amdgcn_global_load_lds((const unsigned int*)(gsrc + c8 * 1024),
                                             ldst + c8 * 256, 16, 0, 0);
        }
    }

    const long mbase  = (long)gb * 64 + wv * 16;
    const bool active = (mbase < NROWS);
    const long mload  = active ? mbase : 0;
    const int c  = lane & 15;
    const int kg = lane >> 4;

    union Af { bf16x8 v; unsigned short u[8]; };
    Af af[4];
    const float* arow = h + (mload + c) * DDIM + kg * 8;
#pragma unroll
    for (int kk = 0; kk < 4; ++kk) {
        float4 x = *(const float4*)(arow + kk * 32);
        float4 y = *(const float4*)(arow + kk * 32 + 4);
        af[kk].u[0] = f2bf(x.x); af[kk].u[1] = f2bf(x.y);
        af[kk].u[2] = f2bf(x.z); af[kk].u[3] = f2bf(x.w);
        af[kk].u[4] = f2bf(y.x); af[kk].u[5] = f2bf(y.y);
        af[kk].u[6] = f2bf(y.z); af[kk].u[7] = f2bf(y.w);
    }
    __syncthreads();
    if (!active) return;

    f32x4 acc[8];
#pragma unroll
    for (int t = 0; t < 8; ++t) acc[t] = (f32x4){0.f, 0.f, 0.f, 0.f};
#pragma unroll
    for (int t = 0; t < 8; ++t) {
        int colbase = (t * 16 + c) * 256;
        int sw = c << 4;
#pragma unroll
        for (int kk = 0; kk < 4; ++kk) {
            int ba = (colbase + kk * 64 + kg * 16) ^ sw;
            bf16x8 b = *(const bf16x8*)(WldsB + ba);
            acc[t] = __builtin_amdgcn_mfma_f32_16x16x32_bf16(af[kk].v, b, acc[t], 0, 0, 0);
        }
    }

#pragma unroll
    for (int t = 0; t < 8; ++t) {
#pragma unroll
        for (int r = 0; r < 4; ++r) {
            int lrow = wv * 16 + kg * 4 + r;
            *(unsigned short*)(stageB + lrow * 272 + (t * 16 + c) * 2) = f2bf(acc[t][r]);
        }
    }
    {
        const long gbase = mbase * 256;
        const int  lbase2 = wv * 16 * 272;
#pragma unroll
        for (int q = 0; q < 4; ++q) {
            int f = q * 1024 + lane * 16;
            uint4 v = *(const uint4*)(stageB + lbase2 + (f >> 8) * 272 + (f & 255));
            *(uint4*)((char*)Wh16 + gbase + f) = v;
        }
    }

    float asv[8], adv[8];
#pragma unroll
    for (int t = 0; t < 8; ++t) {
        asv[t] = Wat[t * 16 + c];
        adv[t] = Wat[DDIM + t * 16 + c];
    }
#pragma unroll
    for (int r = 0; r < 4; ++r) {
        float ps = 0.f, pd = 0.f;
#pragma unroll
        for (int t = 0; t < 8; ++t) {
            ps += acc[t][r] * asv[t];
            pd += acc[t][r] * adv[t];
        }
#pragma unroll
        for (int o = 1; o <= 8; o <<= 1) {
            ps += __shfl_xor(ps, o);
            pd += __shfl_xor(pd, o);
        }
        if (c == 0) {
            long row = mbase + kg * 4 + r;
            ssrc[row] = ps;
            sdst[row] = pd;
        }
    }
}

// ---------------------------------------------------------------------------
// scatterB: per bin — group records by dstlow into LDS, SORT each dst's
// sublist by src (insertion sort, 1 thread/dst), write dense slist + offs.
// Src-sorted lists give cohort-correlated gather locality in aggregate.
// span>CAP fallback: unsorted direct write (ordering is perf-only).
// ---------------------------------------------------------------------------
__global__ __launch_bounds__(256) void scatterB_kernel(const unsigned int* __restrict__ records,
                                                       const int* __restrict__ bintot,
                                                       int* __restrict__ offs,
                                                       int* __restrict__ slist) {
    __shared__ unsigned int S[CAP];            // 18 KB dst-grouped staging
    __shared__ int cnt[128];
    __shared__ int cbase[128];
    __shared__ int bb2[2];
    const int b = blockIdx.x, tid = threadIdx.x;

    if (tid < 64) {                            // wave0: excl scan of bintot
        int carry = 0;
#pragma unroll
        for (int it = 0; it < 7; ++it) {
            int c = it * 64 + tid;
            int v = (c < NBIN) ? bintot[c] : 0;
            int x = v;
#pragma unroll
            for (int o = 1; o < 64; o <<= 1) {
                int t = __shfl_up(x, o);
                if (tid >= o) x += t;
            }
            int excl = carry + x - v;
            if (c == b)     bb2[0] = excl;
            if (c == b + 1) bb2[1] = excl;
            carry += __shfl(x, 63);
        }
    }
    if (tid < 128) cnt[tid] = 0;
    __syncthreads();
    const int start = bb2[0];
    const int span  = bb2[1] - start;

    for (int i = tid; i < span; i += 256)
        atomicAdd(&cnt[records[start + i] >> 16], 1);
    __syncthreads();
    if (tid < 64) {                            // wave0: excl scan of cnt[128]
        int l = tid;
        int c0 = cnt[l], c1 = cnt[64 + l];
        int s0 = c0, s1 = c1;
#pragma unroll
        for (int o = 1; o < 64; o <<= 1) { int t = __shfl_up(s0, o); if (l >= o) s0 += t; }
        int t0 = __shfl(s0, 63);
#pragma unroll
        for (int o = 1; o < 64; o <<= 1) { int t = __shfl_up(s1, o); if (l >= o) s1 += t; }
        cbase[l]      = s0 - c0;
        cbase[64 + l] = t0 + s1 - c1;
    }
    __syncthreads();
    if (tid < 128) {
        offs[b * 128 + tid] = start + cbase[tid];   // covers offs[0..50047]
        cnt[tid] = 0;
    }
    __syncthreads();

    if (span <= CAP) {
        // group into LDS by dstlow
        for (int i = tid; i < span; i += 256) {
            unsigned int r = records[start + i];
            int dl = (int)(r >> 16);
            int pos = atomicAdd(&cnt[dl], 1);
            S[cbase[dl] + pos] = r;
        }
        __syncthreads();
        // per-dst insertion sort by src (uint compare ok: dstlow constant)
        if (tid < 128) {
            int beg = cbase[tid];
            int end = (tid < 127) ? cbase[tid + 1] : span;
            for (int i = beg + 1; i < end; ++i) {
                unsigned int key = S[i];
                int j = i - 1;
                while (j >= beg && S[j] > key) { S[j + 1] = S[j]; --j; }
                S[j + 1] = key;
            }
        }
        __syncthreads();
        for (int i = tid; i < span; i += 256)
            slist[start + i] = (int)(S[i] & 0xFFFFu);
    } else {
        // fallback: unsorted (correct; ordering is a perf hint only)
        for (int i = tid; i < span; i += 256) {
            unsigned int r = records[start + i];
            int dl = (int)(r >> 16);
            int pos = atomicAdd(&cnt[dl], 1);
            slist[start + cbase[dl] + pos] = (int)(r & 0xFFFFu);
        }
    }
}

// ---------------------------------------------------------------------------
// aggregate (r25 proven, 66 us — UNCHANGED): one wave per (dst, batch);
// b = bid&1 XCD steering; 16 lanes/edge x uint4; recomputed weights.
// ---------------------------------------------------------------------------
__global__ __launch_bounds__(256) void aggregate_kernel(const unsigned int* __restrict__ Wh16u,
                                                        const int* __restrict__ offs,
                                                        const int* __restrict__ slist,
                                                        const float* __restrict__ ssrc,
                                                        const float* __restrict__ sdst,
                                                        float* __restrict__ out) {
    const int lane = threadIdx.x & 63;
    const int wid  = threadIdx.x >> 6;
    const int bid  = blockIdx.x;
    const int b    = bid & 1;
    const int d    = (bid >> 1) * 4 + wid;

    const int grp = lane >> 4;
    const int fl  = lane & 15;

    float* o = out + ((long)b * NN + d) * DDIM;

    const int base   = offs[d];
    const int degree = offs[d + 1] - base;
    if (degree == 0) {
        if (lane < 16) {
            float4 z = {0.f, 0.f, 0.f, 0.f};
            ((float4*)o)[2 * fl]     = z;
            ((float4*)o)[2 * fl + 1] = z;
        }
        return;
    }

    const long boff = (long)b * NN;
    const float sdv = sdst[boff + d];
    const float* ssb = ssrc + boff;
    const unsigned int* WB = Wh16u + boff * 64;

    f32x4 accA = {0,0,0,0}, accB = {0,0,0,0};
    float ds = 0.f;

    for (int ch = 0; ch < degree; ch += 64) {
        int i = ch + lane;
        int s = 0; float w = 0.f;
        if (i < degree) {
            s = slist[base + i];
            w = __expf(lrelu(ssb[s] + sdv));
            ds += w;
        }
        int cnt   = min(64, degree - ch);
        int quads = (cnt + 3) >> 2;
        for (int j = 0; j < quads; ++j) {
            int idx = 4 * j + grp;
            int   sj = __shfl(s, idx);
            float wj = __shfl(w, idx);
            uint4 v = ((const uint4*)(WB + (long)sj * 64))[fl];
            accA.x += wj * bflo(v.x); accA.y += wj * bfhi(v.x);
            accA.z += wj * bflo(v.y); accA.w += wj * bfhi(v.y);
            accB.x += wj * bflo(v.z); accB.y += wj * bfhi(v.z);
            accB.z += wj * bflo(v.w); accB.w += wj * bfhi(v.w);
        }
    }

#pragma unroll
    for (int m = 32; m >= 16; m >>= 1) {
        accA.x += __shfl_xor(accA.x, m); accA.y += __shfl_xor(accA.y, m);
        accA.z += __shfl_xor(accA.z, m); accA.w += __shfl_xor(accA.w, m);
        accB.x += __shfl_xor(accB.x, m); accB.y += __shfl_xor(accB.y, m);
        accB.z += __shfl_xor(accB.z, m); accB.w += __shfl_xor(accB.w, m);
    }
#pragma unroll
    for (int m = 32; m > 0; m >>= 1) ds += __shfl_xor(ds, m);
    const float inv = 1.f / ds;

    if (lane < 16) {
        float4 rA = { eluf(accA.x * inv), eluf(accA.y * inv),
                      eluf(accA.z * inv), eluf(accA.w * inv) };
        float4 rB = { eluf(accB.x * inv), eluf(accB.y * inv),
                      eluf(accB.z * inv), eluf(accB.w * inv) };
        ((float4*)o)[2 * fl]     = rA;
        ((float4*)o)[2 * fl + 1] = rB;
    }
}

// ---------------------------------------------------------------------------
extern "C" void kernel_launch(void* const* d_in, const int* in_sizes, int n_in,
                              void* d_out, int out_size, void* d_ws, size_t ws_size,
                              hipStream_t stream) {
    (void)in_sizes; (void)n_in; (void)out_size; (void)ws_size;
    const float* h   = (const float*)d_in[0];
    const int*   ei  = (const int*)d_in[1];
    const float* Wfc = (const float*)d_in[2];
    const float* Wat = (const float*)d_in[3];
    float* out = (float*)d_out;

    char* ws = (char*)d_ws;
    unsigned short* Wh16 = (unsigned short*)(ws + 0);       // 25,600,000 B
    float*  ssrc  = (float*)(ws + 25600000);                //    400,000 B
    float*  sdst  = (float*)(ws + 26000000);                //    400,000 B
    int*    slist = (int*)  (ws + 26400000);                //  3,200,000 B
    unsigned int* records = (unsigned int*)(ws + 29600000); //  3,200,000 B
    int*    offs      = (int*)(ws + 32800000);              //    200,192 B (50048)
    int*    histmat   = (int*)(ws + 33000192);              //    611,524 B
    int*    chunkstart= (int*)(ws + 33611716);              //    611,524 B
    int*    bintot    = (int*)(ws + 34223240);              //      1,564 B
    unsigned short* Wsw = (unsigned short*)(ws + 34224816); //     32,768 B (16B-aligned)

    histW_kernel<<<NCHUNK + 1, 256, 0, stream>>>(ei, histmat, Wfc, Wsw);
    colscan_kernel<<<NBIN, 64, 0, stream>>>(histmat, chunkstart, bintot);
    fusedAG_kernel<<<NCHUNK + GEMMB, 256, 0, stream>>>(ei, bintot, chunkstart, records,
                                                       h, Wsw, Wat, Wh16, ssrc, sdst);
    scatterB_kernel<<<NBIN, 256, 0, stream>>>(records, bintot, offs, slist);
    aggregate_kernel<<<25000, 256, 0, stream>>>((const unsigned int*)Wh16, offs,
                                                slist, ssrc, sdst, out);
}

// Round 28
// 111.125 us; speedup vs baseline: 1.3304x; 1.3304x over previous
//
#include <hip/hip_runtime.h>
#include <math.h>

#define NN 50000
#define EE 800000
#define DDIM 128
#define NROWS 100000   // B*N
#define NBIN 391       // ceil(NN/128) sort bins (128 dsts each)
#define NCHUNK 391     // ceil(EE/2048) edge chunks (2048 edges each)
#define GEMMB 1563     // ceil(NROWS/64)

typedef __attribute__((ext_vector_type(8))) short bf16x8;
typedef __attribute__((ext_vector_type(4))) float f32x4;

__device__ __forceinline__ float lrelu(float x) { return x > 0.f ? x : 0.2f * x; }
// fast ELU via hardware v_exp_f32 (abs err ~1e-7, validated r13)
__device__ __forceinline__ float eluf(float x)  {
    float e = __expf(x);
    return x > 0.f ? x : e - 1.f;
}

__device__ __forceinline__ unsigned short f2bf(float f) {
    unsigned int u = __float_as_uint(f);
    u += 0x7fffu + ((u >> 16) & 1u);          // RNE
    return (unsigned short)(u >> 16);
}
__device__ __forceinline__ float bflo(unsigned int v) { return __uint_as_float(v << 16); }
__device__ __forceinline__ float bfhi(unsigned int v) { return __uint_as_float(v & 0xffff0000u); }

// ---------------------------------------------------------------------------
// histW: blocks [0,NCHUNK): per-chunk LDS histogram of dst>>7 -> private row
// histmat[chunk][bin]. Block NCHUNK: W fp32 -> bf16 pre-swizzled.
// ---------------------------------------------------------------------------
__global__ __launch_bounds__(256) void histW_kernel(const int* __restrict__ ei,
                                                    int* __restrict__ histmat,
                                                    const float* __restrict__ Wfc,
                                                    unsigned short* __restrict__ Wsw) {
    const int tid = threadIdx.x;
    if (blockIdx.x < NCHUNK) {
        __shared__ int lcnt[NBIN];
        for (int i = tid; i < NBIN; i += 256) lcnt[i] = 0;
        __syncthreads();
        const int cb  = blockIdx.x * 2048;
        const int cnt = min(2048, EE - cb);
#pragma unroll
        for (int r = 0; r < 8; ++r) {
            int el = r * 256 + tid;
            if (el < cnt) atomicAdd(&lcnt[ei[EE + cb + el] >> 7], 1);
        }
        __syncthreads();
        for (int i = tid; i < NBIN; i += 256)
            histmat[blockIdx.x * NBIN + i] = lcnt[i];
        return;
    }
    // W prep (one block)
    const int col = tid & 127;
    const int kh  = tid >> 7;                  // 0..1
#pragma unroll
    for (int q8 = 0; q8 < 8; ++q8) {
        int k0 = kh * 64 + q8 * 8;
        float4 w0 = *(const float4*)&Wfc[col * DDIM + k0];
        float4 w1 = *(const float4*)&Wfc[col * DDIM + k0 + 4];
        union { uint4 q4; unsigned short u[8]; } pk;
        pk.u[0] = f2bf(w0.x); pk.u[1] = f2bf(w0.y);
        pk.u[2] = f2bf(w0.z); pk.u[3] = f2bf(w0.w);
        pk.u[4] = f2bf(w1.x); pk.u[5] = f2bf(w1.y);
        pk.u[6] = f2bf(w1.z); pk.u[7] = f2bf(w1.w);
        int chunk = (k0 >> 3) ^ (col & 15);
        *(uint4*)((char*)Wsw + col * 256 + chunk * 16) = pk.q4;
    }
}

// ---------------------------------------------------------------------------
// colscan: one wave per bin — exclusive prefix over chunk counts.
// ---------------------------------------------------------------------------
__global__ __launch_bounds__(64) void colscan_kernel(const int* __restrict__ histmat,
                                                     int* __restrict__ chunkstart,
                                                     int* __restrict__ bintot) {
    const int bin  = blockIdx.x;
    const int lane = threadIdx.x;
    int carry = 0;
#pragma unroll
    for (int it = 0; it < 7; ++it) {           // 7*64 = 448 >= NCHUNK
        int c = it * 64 + lane;
        int v = (c < NCHUNK) ? histmat[c * NBIN + bin] : 0;
        int x = v;
#pragma unroll
        for (int o = 1; o < 64; o <<= 1) {
            int t = __shfl_up(x, o);
            if (lane >= o) x += t;
        }
        if (c < NCHUNK) chunkstart[bin * NCHUNK + c] = carry + x - v;
        carry += __shfl(x, 63);
    }
    if (lane == 0) bintot[bin] = carry;
}

// ---------------------------------------------------------------------------
// fusedAG: blocks [0,NCHUNK) = scatterA; blocks [NCHUNK,+GEMMB) = MFMA gemm.
// ---------------------------------------------------------------------------
__global__ __launch_bounds__(256) void fusedAG_kernel(const int* __restrict__ ei,
                                                      const int* __restrict__ bintot,
                                                      const int* __restrict__ chunkstart,
                                                      unsigned int* __restrict__ records,
                                                      const float* __restrict__ h,
                                                      const unsigned short* __restrict__ Wsw,
                                                      const float* __restrict__ Wat,
                                                      unsigned short* __restrict__ Wh16,
                                                      float* __restrict__ ssrc,
                                                      float* __restrict__ sdst) {
    __shared__ unsigned int Wlds_u32[8192];    // 32 KB: gemm W / scatterA tables
    __shared__ unsigned short stage[64 * 136]; // 17408 B (gemm epilogue)
    const int tid = threadIdx.x;

    if (blockIdx.x < NCHUNK) {
        // ---- scatterA path ----
        int* lcnt  = (int*)Wlds_u32;           // [0, 391)
        int* lbase = (int*)Wlds_u32 + 512;     // [512, 903)
        int* bb    = (int*)Wlds_u32 + 1024;    // [1024, 1415)
        if (tid < 64) {                        // wave0: excl scan of bintot
            int carry = 0;
#pragma unroll
            for (int it = 0; it < 7; ++it) {
                int c = it * 64 + tid;
                int v = (c < NBIN) ? bintot[c] : 0;
                int x = v;
#pragma unroll
                for (int o = 1; o < 64; o <<= 1) {
                    int t = __shfl_up(x, o);
                    if (tid >= o) x += t;
                }
                if (c < NBIN) bb[c] = carry + x - v;
                carry += __shfl(x, 63);
            }
        }
        __syncthreads();
        for (int i = tid; i < NBIN; i += 256) {
            lcnt[i]  = 0;
            lbase[i] = bb[i] + chunkstart[i * NCHUNK + blockIdx.x];
        }
        __syncthreads();
        const int cb  = blockIdx.x * 2048;
        const int cnt = min(2048, EE - cb);
#pragma unroll
        for (int r = 0; r < 8; ++r) {
            int el = r * 256 + tid;
            if (el < cnt) {
                int e   = cb + el;
                int dst = ei[EE + e];
                int src = ei[e];
                int bin = dst >> 7;
                int rank = atomicAdd(&lcnt[bin], 1);
                records[lbase[bin] + rank] = (unsigned)src | ((unsigned)(dst & 127) << 16);
            }
        }
        return;
    }

    // ---- gemm path (r25 proven) ----
    char* WldsB  = (char*)Wlds_u32;
    char* stageB = (char*)stage;
    const int gb   = blockIdx.x - NCHUNK;
    const int lane = tid & 63;
    const int wv   = tid >> 6;

    {
        const char* gsrc = (const char*)Wsw + wv * 8192 + lane * 16;
        unsigned int* ldst = &Wlds_u32[wv * 2048];
#pragma unroll
        for (int c8 = 0; c8 < 8; ++c8) {
            __builtin_amdgcn_global_load_lds((const unsigned int*)(gsrc + c8 * 1024),
                                             ldst + c8 * 256, 16, 0, 0);
        }
    }

    const long mbase  = (long)gb * 64 + wv * 16;
    const bool active = (mbase < NROWS);
    const long mload  = active ? mbase : 0;
    const int c  = lane & 15;
    const int kg = lane >> 4;

    union Af { bf16x8 v; unsigned short u[8]; };
    Af af[4];
    const float* arow = h + (mload + c) * DDIM + kg * 8;
#pragma unroll
    for (int kk = 0; kk < 4; ++kk) {
        float4 x = *(const float4*)(arow + kk * 32);
        float4 y = *(const float4*)(arow + kk * 32 + 4);
        af[kk].u[0] = f2bf(x.x); af[kk].u[1] = f2bf(x.y);
        af[kk].u[2] = f2bf(x.z); af[kk].u[3] = f2bf(x.w);
        af[kk].u[4] = f2bf(y.x); af[kk].u[5] = f2bf(y.y);
        af[kk].u[6] = f2bf(y.z); af[kk].u[7] = f2bf(y.w);
    }
    __syncthreads();
    if (!active) return;

    f32x4 acc[8];
#pragma unroll
    for (int t = 0; t < 8; ++t) acc[t] = (f32x4){0.f, 0.f, 0.f, 0.f};
#pragma unroll
    for (int t = 0; t < 8; ++t) {
        int colbase = (t * 16 + c) * 256;
        int sw = c << 4;
#pragma unroll
        for (int kk = 0; kk < 4; ++kk) {
            int ba = (colbase + kk * 64 + kg * 16) ^ sw;
            bf16x8 b = *(const bf16x8*)(WldsB + ba);
            acc[t] = __builtin_amdgcn_mfma_f32_16x16x32_bf16(af[kk].v, b, acc[t], 0, 0, 0);
        }
    }

#pragma unroll
    for (int t = 0; t < 8; ++t) {
#pragma unroll
        for (int r = 0; r < 4; ++r) {
            int lrow = wv * 16 + kg * 4 + r;
            *(unsigned short*)(stageB + lrow * 272 + (t * 16 + c) * 2) = f2bf(acc[t][r]);
        }
    }
    {
        const long gbase = mbase * 256;
        const int  lbase2 = wv * 16 * 272;
#pragma unroll
        for (int q = 0; q < 4; ++q) {
            int f = q * 1024 + lane * 16;
            uint4 v = *(const uint4*)(stageB + lbase2 + (f >> 8) * 272 + (f & 255));
            *(uint4*)((char*)Wh16 + gbase + f) = v;
        }
    }

    float asv[8], adv[8];
#pragma unroll
    for (int t = 0; t < 8; ++t) {
        asv[t] = Wat[t * 16 + c];
        adv[t] = Wat[DDIM + t * 16 + c];
    }
#pragma unroll
    for (int r = 0; r < 4; ++r) {
        float ps = 0.f, pd = 0.f;
#pragma unroll
        for (int t = 0; t < 8; ++t) {
            ps += acc[t][r] * asv[t];
            pd += acc[t][r] * adv[t];
        }
#pragma unroll
        for (int o = 1; o <= 8; o <<= 1) {
            ps += __shfl_xor(ps, o);
            pd += __shfl_xor(pd, o);
        }
        if (c == 0) {
            long row = mbase + kg * 4 + r;
            ssrc[row] = ps;
            sdst[row] = pd;
        }
    }
}

// ---------------------------------------------------------------------------
// scatterB: per bin two-pass LDS counting sort -> dense slist + CSR offs.
// (r26 proven — no src sorting; r27 falsified its value.)
// ---------------------------------------------------------------------------
__global__ __launch_bounds__(256) void scatterB_kernel(const unsigned int* __restrict__ records,
                                                       const int* __restrict__ bintot,
                                                       int* __restrict__ offs,
                                                       int* __restrict__ slist) {
    __shared__ int cnt[128];
    __shared__ int cbase[128];
    __shared__ int bb2[2];
    const int b = blockIdx.x, tid = threadIdx.x;

    if (tid < 64) {                            // wave0: excl scan of bintot
        int carry = 0;
#pragma unroll
        for (int it = 0; it < 7; ++it) {
            int c = it * 64 + tid;
            int v = (c < NBIN) ? bintot[c] : 0;
            int x = v;
#pragma unroll
            for (int o = 1; o < 64; o <<= 1) {
                int t = __shfl_up(x, o);
                if (tid >= o) x += t;
            }
            int excl = carry + x - v;          // c>=NBIN: v=0 -> excl = total
            if (c == b)     bb2[0] = excl;
            if (c == b + 1) bb2[1] = excl;
            carry += __shfl(x, 63);
        }
    }
    if (tid < 128) cnt[tid] = 0;
    __syncthreads();
    const int start = bb2[0];
    const int span  = bb2[1] - start;

    for (int i = tid; i < span; i += 256)
        atomicAdd(&cnt[records[start + i] >> 16], 1);
    __syncthreads();
    if (tid < 64) {
        int l = tid;
        int c0 = cnt[l], c1 = cnt[64 + l];
        int s0 = c0, s1 = c1;
#pragma unroll
        for (int o = 1; o < 64; o <<= 1) { int t = __shfl_up(s0, o); if (l >= o) s0 += t; }
        int t0 = __shfl(s0, 63);
#pragma unroll
        for (int o = 1; o < 64; o <<= 1) { int t = __shfl_up(s1, o); if (l >= o) s1 += t; }
        cbase[l]      = s0 - c0;
        cbase[64 + l] = t0 + s1 - c1;
    }
    __syncthreads();
    if (tid < 128) {
        offs[b * 128 + tid] = start + cbase[tid];   // covers offs[0..50047]
        cnt[tid] = 0;
    }
    __syncthreads();
    for (int i = tid; i < span; i += 256) {
        unsigned int r = records[start + i];
        int dl = (int)(r >> 16);
        int pos = atomicAdd(&cnt[dl], 1);
        slist[start + cbase[dl] + pos] = (int)(r & 0xFFFFu);
    }
}

// ---------------------------------------------------------------------------
// aggregate (r26 structure + NONTEMPORAL out stores): one wave per
// (dst, batch); b = bid&1 XCD steering; 16 lanes/edge x uint4; recomputed
// weights. Nontemporal stores keep the 50 MB output stream from evicting
// gather-table lines in L2.
// ---------------------------------------------------------------------------
__global__ __launch_bounds__(256) void aggregate_kernel(const unsigned int* __restrict__ Wh16u,
                                                        const int* __restrict__ offs,
                                                        const int* __restrict__ slist,
                                                        const float* __restrict__ ssrc,
                                                        const float* __restrict__ sdst,
                                                        float* __restrict__ out) {
    const int lane = threadIdx.x & 63;
    const int wid  = threadIdx.x >> 6;
    const int bid  = blockIdx.x;
    const int b    = bid & 1;
    const int d    = (bid >> 1) * 4 + wid;

    const int grp = lane >> 4;
    const int fl  = lane & 15;

    float* o = out + ((long)b * NN + d) * DDIM;

    const int base   = offs[d];
    const int degree = offs[d + 1] - base;
    if (degree == 0) {
        if (lane < 16) {
            f32x4 z = {0.f, 0.f, 0.f, 0.f};
            __builtin_nontemporal_store(z, (f32x4*)o + 2 * fl);
            __builtin_nontemporal_store(z, (f32x4*)o + 2 * fl + 1);
        }
        return;
    }

    const long boff = (long)b * NN;
    const float sdv = sdst[boff + d];
    const float* ssb = ssrc + boff;
    const unsigned int* WB = Wh16u + boff * 64;

    f32x4 accA = {0,0,0,0}, accB = {0,0,0,0};
    float ds = 0.f;

    for (int ch = 0; ch < degree; ch += 64) {
        int i = ch + lane;
        int s = 0; float w = 0.f;
        if (i < degree) {
            s = slist[base + i];
            w = __expf(lrelu(ssb[s] + sdv));
            ds += w;
        }
        int cnt   = min(64, degree - ch);
        int quads = (cnt + 3) >> 2;
        for (int j = 0; j < quads; ++j) {
            int idx = 4 * j + grp;
            int   sj = __shfl(s, idx);
            float wj = __shfl(w, idx);
            uint4 v = ((const uint4*)(WB + (long)sj * 64))[fl];
            accA.x += wj * bflo(v.x); accA.y += wj * bfhi(v.x);
            accA.z += wj * bflo(v.y); accA.w += wj * bfhi(v.y);
            accB.x += wj * bflo(v.z); accB.y += wj * bfhi(v.z);
            accB.z += wj * bflo(v.w); accB.w += wj * bfhi(v.w);
        }
    }

#pragma unroll
    for (int m = 32; m >= 16; m >>= 1) {
        accA.x += __shfl_xor(accA.x, m); accA.y += __shfl_xor(accA.y, m);
        accA.z += __shfl_xor(accA.z, m); accA.w += __shfl_xor(accA.w, m);
        accB.x += __shfl_xor(accB.x, m); accB.y += __shfl_xor(accB.y, m);
        accB.z += __shfl_xor(accB.z, m); accB.w += __shfl_xor(accB.w, m);
    }
#pragma unroll
    for (int m = 32; m > 0; m >>= 1) ds += __shfl_xor(ds, m);
    const float inv = 1.f / ds;

    if (lane < 16) {
        f32x4 rA = { eluf(accA.x * inv), eluf(accA.y * inv),
                     eluf(accA.z * inv), eluf(accA.w * inv) };
        f32x4 rB = { eluf(accB.x * inv), eluf(accB.y * inv),
                     eluf(accB.z * inv), eluf(accB.w * inv) };
        __builtin_nontemporal_store(rA, (f32x4*)o + 2 * fl);
        __builtin_nontemporal_store(rB, (f32x4*)o + 2 * fl + 1);
    }
}

// ---------------------------------------------------------------------------
extern "C" void kernel_launch(void* const* d_in, const int* in_sizes, int n_in,
                              void* d_out, int out_size, void* d_ws, size_t ws_size,
                              hipStream_t stream) {
    (void)in_sizes; (void)n_in; (void)out_size; (void)ws_size;
    const float* h   = (const float*)d_in[0];
    const int*   ei  = (const int*)d_in[1];
    const float* Wfc = (const float*)d_in[2];
    const float* Wat = (const float*)d_in[3];
    float* out = (float*)d_out;

    char* ws = (char*)d_ws;
    unsigned short* Wh16 = (unsigned short*)(ws + 0);       // 25,600,000 B
    float*  ssrc  = (float*)(ws + 25600000);                //    400,000 B
    float*  sdst  = (float*)(ws + 26000000);                //    400,000 B
    int*    slist = (int*)  (ws + 26400000);                //  3,200,000 B
    unsigned int* records = (unsigned int*)(ws + 29600000); //  3,200,000 B
    int*    offs      = (int*)(ws + 32800000);              //    200,192 B (50048)
    int*    histmat   = (int*)(ws + 33000192);              //    611,524 B
    int*    chunkstart= (int*)(ws + 33611716);              //    611,524 B
    int*    bintot    = (int*)(ws + 34223240);              //      1,564 B
    unsigned short* Wsw = (unsigned short*)(ws + 34224816); //     32,768 B (16B-aligned)

    histW_kernel<<<NCHUNK + 1, 256, 0, stream>>>(ei, histmat, Wfc, Wsw);
    colscan_kernel<<<NBIN, 64, 0, stream>>>(histmat, chunkstart, bintot);
    fusedAG_kernel<<<NCHUNK + GEMMB, 256, 0, stream>>>(ei, bintot, chunkstart, records,
                                                       h, Wsw, Wat, Wh16, ssrc, sdst);
    scatterB_kernel<<<NBIN, 256, 0, stream>>>(records, bintot, offs, slist);
    aggregate_kernel<<<25000, 256, 0, stream>>>((const unsigned int*)Wh16, offs,
                                                slist, ssrc, sdst, out);
}